// Round 5
// baseline (302.228 us; speedup 1.0000x reference)
//
#include <hip/hip_runtime.h>
#include <hip/hip_bf16.h>
#include <stdint.h>
#include <stddef.h>

// SimpleStateSpaceModel: B=4, S=4096, D=1024. FP32 in/out; bf16 MFMA inside.
// Pipeline (106 MB of d_ws):
//   C0 cast_all         : x->xb (32MB), {dt_w,B_w,C_w}->wcat (6MB)
//   K1 gemm8<bf16>      : P[m,0:1024]=x@dt_w^T, P[m,1024:2048]=x@B_w^T
//   S1 scan_local       : g,u from (P,xb); in-place P <- [hl(t) | pg(t)]
//   S2 scan_carry       : sequential combine over 128 chunks
//   S3 scan_fix         : h(t) = hl(t) + carry*pg(t)
//   K6 gemm8<f32>       : out = h@C_w^T + D*x (xb epilogue)
// R5: MFMA shape 16x16x32 -> 32x32x16 (µbench 2382 vs 2075 TF; half the
// MFMA instruction count per phase, same LDS read count). Schedule, staging,
// waits, swizzle identical to R4. A/B frag: row/col=lane&31, k=(lane>>5)*8+j.
// C/D: col=lane&31, row=(reg&3)+8*(reg>>2)+4*(lane>>5) [m74/m101].

#define Bdim 4
#define Sdim 4096
#define Dd   1024
#define Mdim (Bdim * Sdim)      // 16384
#define CCH  128                // scan chunks per sequence
#define LCH  (Sdim / CCH)       // 32 steps per chunk

typedef __attribute__((ext_vector_type(8)))  short short8;
typedef __attribute__((ext_vector_type(4)))  short short4v;
typedef __attribute__((ext_vector_type(4)))  float floatx4;
typedef __attribute__((ext_vector_type(16))) float floatx16;

#if __has_builtin(__builtin_amdgcn_exp2f)
#define EXP2(x) __builtin_amdgcn_exp2f(x)
#else
#define EXP2(x) exp2f(x)
#endif
#if __has_builtin(__builtin_amdgcn_logf)
#define LOG2(x) __builtin_amdgcn_logf(x)
#else
#define LOG2(x) __log2f(x)
#endif
#define LOG2E 1.44269504088896f
#define LN2   0.69314718055995f

__device__ __forceinline__ float b2f(short v) {
  unsigned u = ((unsigned)(unsigned short)v) << 16;
  float f; __builtin_memcpy(&f, &u, 4); return f;
}
// HW RNE bf16 convert
__device__ __forceinline__ short f2b(float f) {
  __hip_bfloat16 h = __float2bfloat16(f);
  short s; __builtin_memcpy(&s, &h, 2); return s;
}

__device__ __forceinline__ short8 ld8f(const float* p) {
  floatx4 lo = *(const floatx4*)p;
  floatx4 hi = *(const floatx4*)(p + 4);
  short8 r;
  r[0] = f2b(lo[0]); r[1] = f2b(lo[1]); r[2] = f2b(lo[2]); r[3] = f2b(lo[3]);
  r[4] = f2b(hi[0]); r[5] = f2b(hi[1]); r[6] = f2b(hi[2]); r[7] = f2b(hi[3]);
  return r;
}

__device__ __forceinline__ void st_out(short* p, float v) { *p = f2b(v); }
__device__ __forceinline__ void st_out(float* p, float v) { *p = v; }

// async 16B global->LDS (DMA). lds dest wave-uniform; lane i -> l + i*16. [m97]
__device__ __forceinline__ void cp16(const void* g, void* l) {
  __builtin_amdgcn_global_load_lds(
      (__attribute__((address_space(1))) void*)g,
      (__attribute__((address_space(3))) void*)l, 16, 0, 0);
}

// ---------------------------------------------------------------------------
// gemm8: Out[m,n] = sum_k A[m,k]*W[n,k], A/W bf16, K=1024 (NT=16 K-tiles).
// 256x256 tile, BK=64, 8 waves (2M x 4N), per-wave 128x64 output.
// R4 schedule: per tile 4 phases = C-quadrants (0,0),(0,1),(1,1),(1,0);
// phase = {WBAR(vmcnt4+barrier); ds_read frags; stage next half-tile; MFMA}.
// Steady state 6-8 loads in flight; vmcnt never 0 except epilogue.
// MFMA = 32x32x16_bf16: per phase 2 m-frags x 1 n-frag x 4 ks = 8 MFMA.
// ---------------------------------------------------------------------------
#define STGA(bufB, h, kk) do { \
  cp16(Ag + (size_t)((h) * 64) * lda + (kk), \
       smc + (bufB) + ((h) * 64 + ldsArow) * 128); \
  cp16(Ag + (size_t)((h) * 64 + 128) * lda + (kk), \
       smc + (bufB) + ((h) * 64 + 128 + ldsArow) * 128); \
} while (0)

#define STGB(bufB, h, kk) do { \
  cp16(Bg + (size_t)((h) * 32) * ldw + (kk), \
       smc + (bufB) + ((h) * 32 + ldsBrow) * 128); \
  cp16(Bg + (size_t)((h) * 32 + 128) * ldw + (kk), \
       smc + (bufB) + ((h) * 32 + 128 + ldsBrow) * 128); \
} while (0)

// A-frags for quadrant row mh: 2 x 32-row frags (rows bit6 == mh), 4 ks each
#define LDA2(bufB, mh) do { \
  _Pragma("unroll") \
  for (int f = 0; f < 2; ++f) { \
    const char* p_ = smc + (bufB) + (wm + ((mh) * 2 + f) * 32 + l32) * 128; \
    _Pragma("unroll") \
    for (int ks = 0; ks < 4; ++ks) \
      a[f][ks] = *(const short8*)(p_ + cx[ks]); \
  } \
} while (0)

// B-frag for quadrant col nh: 1 x 32-col frag (rows bit5 == nh), 4 ks
#define LDB1(bufB, nh, bb) do { \
  const char* p_ = smc + (bufB) + (wn + (nh) * 32 + l32) * 128; \
  _Pragma("unroll") \
  for (int ks = 0; ks < 4; ++ks) \
    bb[ks] = *(const short8*)(p_ + cx[ks]); \
} while (0)

// 8-MFMA cluster (one C-quadrant over K=64), 32x32x16. setprio (T5);
// trailing sched_barrier keeps the cluster ahead of the next raw s_barrier.
#define MM8(mh, nh, bb) do { \
  __builtin_amdgcn_s_setprio(1); \
  _Pragma("unroll") \
  for (int ks = 0; ks < 4; ++ks) { \
    _Pragma("unroll") \
    for (int f = 0; f < 2; ++f) { \
      acc[(mh) * 2 + f][nh] = __builtin_amdgcn_mfma_f32_32x32x16_bf16( \
          a[f][ks], bb[ks], acc[(mh) * 2 + f][nh], 0, 0, 0); \
    } \
  } \
  __builtin_amdgcn_s_setprio(0); \
  __builtin_amdgcn_sched_barrier(0); \
} while (0)

#define WBAR(n) asm volatile("s_waitcnt vmcnt(" n ")\n\ts_barrier" ::: "memory")
#define BARO()  asm volatile("s_barrier" ::: "memory")

// one full K-tile, all staging unconditional (hot loop only).
#define KSTEP(AB, BBUF, AN, BN, kk) do { \
  WBAR("4"); \
  LDA2(AB, 0); \
  LDB1(BBUF, 0, b0); \
  STGA(AN, 0, kk); \
  MM8(0, 0, b0); \
  WBAR("4"); \
  LDB1(BBUF, 1, b1); \
  STGB(BN, 0, kk); \
  MM8(0, 1, b1); \
  WBAR("4"); \
  LDA2(AB, 1); \
  STGB(BN, 1, kk); \
  MM8(1, 1, b1); \
  BARO(); \
  STGA(AN, 1, kk); \
  MM8(1, 0, b0); \
} while (0)

template <typename OT, bool FUSE>
__global__ __launch_bounds__(512, 2) void gemm8(
    const short* __restrict__ A, int lda,
    const short* __restrict__ W, int ldw,    // bf16 [N][K] row-major
    OT* __restrict__ Out, int ldo,
    const float* __restrict__ Dp, const short* __restrict__ Xr, int ldx)
{
  __shared__ short smem[65536];   // 128 KiB: Abuf0|Abuf1|Bbuf0|Bbuf1, 32K each
  char* smc = (char*)smem;

  const int tid  = threadIdx.x;
  const int lane = tid & 63, wv = tid >> 6;
  const int l32  = lane & 31;
  const int hi   = lane >> 5;             // k-half select for 32x32 frags
  const int wm = (wv & 1) << 7;           // 0 / 128
  const int wn = (wv >> 1) << 6;          // 0,64,128,192
  const int m0 = blockIdx.x << 8;
  const int n0 = blockIdx.y << 8;

  // read-side swizzle: phys col-byte = logical ^ ((row&7)<<4); row&7 == lane&7
  const int sx = (lane & 7) << 4;
  int cx[4];
#pragma unroll
  for (int ks = 0; ks < 4; ++ks)
    cx[ks] = ((ks << 5) | (hi << 4)) ^ sx;   // frag (ks): bytes ks*32 + hi*16

  // per-thread staging source bases (pre-swizzled global column)
  const int r0 = tid >> 3;                                  // 0..63
  const int sk = (((tid & 7) ^ (r0 & 7)) << 3);             // elems, <64
  const short* Ag = A + (size_t)(m0 + r0) * lda + sk;
  const short* Bg = W + (size_t)(n0 + ((r0 >> 5) << 6) + (r0 & 31)) * ldw + sk;
  const int ldsArow = wv << 3;                              // wave-uniform
  const int ldsBrow = ((wv >> 2) << 6) + ((wv << 3) & 31);  // wave-uniform

  short8 a[2][4], b0[4], b1[4];
  floatx16 acc[4][2] = {};

  // prologue: stage tile 0 into buf0, consumption order A0, B0, B1, A1
  STGA(0, 0, 0);
  STGB(65536, 0, 0);
  STGB(65536, 1, 0);
  STGA(0, 1, 0);

  // hot loop: tiles 0..13, 2 per iteration, literal buffer bases.
  for (int t = 0; t < 14; t += 2) {
    KSTEP(0,     65536, 32768, 98304, (t + 1) << 6);
    KSTEP(32768, 98304, 0,     65536, (t + 2) << 6);
  }
  // tile 14 (even, still stages tile 15)
  KSTEP(0, 65536, 32768, 98304, 15 << 6);

  // tile 15 epilogue (cb=1, no staging; drain 4 -> 2 -> 0)
  WBAR("4");
  LDA2(32768, 0);
  LDB1(98304, 0, b0);
  MM8(0, 0, b0);
  WBAR("2");
  LDB1(98304, 1, b1);
  MM8(0, 1, b1);
  WBAR("0");
  LDA2(32768, 1);
  MM8(1, 1, b1);
  BARO();
  MM8(1, 0, b0);

  // C/D layout (32x32): col = l32, row = (r&3) + 8*(r>>2) + 4*hi  [m74/m101]
#pragma unroll
  for (int mf = 0; mf < 4; ++mf) {
#pragma unroll
    for (int g = 0; g < 2; ++g) {
#pragma unroll
      for (int r = 0; r < 16; ++r) {
        int m = m0 + wm + mf * 32 + (r & 3) + 8 * (r >> 2) + 4 * hi;
        int n = n0 + wn + g * 32 + l32;
        float v = acc[mf][g][r];
        if (FUSE) v += Dp[n] * b2f(Xr[(size_t)m * ldx + n]);
        st_out(Out + (size_t)m * ldo + n, v);
      }
    }
  }
}

// ---------------------------------------------------------------------------
// C0: fused cast fp32->bf16 for x (16M elems) and the 3 weights (1M each).
// ---------------------------------------------------------------------------
__global__ __launch_bounds__(256) void cast_all(
    const float* __restrict__ x, const float* __restrict__ dt_w,
    const float* __restrict__ B_w, const float* __restrict__ C_w,
    short* __restrict__ xb, short* __restrict__ wcat)
{
  size_t i = ((size_t)blockIdx.x * 256 + threadIdx.x) * 8;
  const size_t NX = (size_t)Mdim * Dd;           // 16,777,216
  const size_t NW = (size_t)Dd * Dd;             // 1,048,576
  if (i < NX) {
    *(short8*)(xb + i) = ld8f(x + i);
  } else {
    size_t j = i - NX;
    const float* src = (j < NW) ? (dt_w + j)
                     : (j < 2 * NW) ? (B_w + (j - NW))
                                    : (C_w + (j - 2 * NW));
    *(short8*)(wcat + j) = ld8f(src);
  }
}

// ---------------------------------------------------------------------------
// S1: single transcendental pass, 1 d per thread (8192 waves).
// Gate math: z = dt_pre + dt_b; e = 2^(z*log2e); L = log2(1+e);
//   sp = ln2*L (softplus); g = 2^(nA*L)  [= exp(sp*nA)]; u = sp*Bp*x.
// ---------------------------------------------------------------------------
__global__ __launch_bounds__(256) void scan_local(
    short* __restrict__ P, const short* __restrict__ xb,
    const float* __restrict__ dt_b, const float* __restrict__ A_log,
    const float* __restrict__ h0,
    float* __restrict__ Pc, float* __restrict__ Hl)
{
  const int b = blockIdx.x >> 7;
  const int c = blockIdx.x & 127;
  const int d = blockIdx.y * 256 + threadIdx.x;

  const float db = dt_b[d];
  const float nA = -EXP2(A_log[d] * LOG2E);

  const size_t mrow = (size_t)b * Sdim + (size_t)c * LCH;
  short* pp = P + mrow * 2048 + d;           // dt slot; +1024 = Bp slot
  const short* px = xb + mrow * 1024 + d;

  float p = 1.f, h = 0.f;
  short dt_c = pp[0], bp_c = pp[1024], xv_c = px[0];
  for (int t = 0; t < LCH; ++t) {
    short dt_n = 0, bp_n = 0, xv_n = 0;
    if (t + 1 < LCH) {                       // prefetch above the serial chain
      dt_n = pp[2048]; bp_n = pp[2048 + 1024]; xv_n = px[1024];
    }
    float z  = b2f(dt_c) + db;
    float e  = EXP2(z * LOG2E);
    float L  = LOG2(1.f + e);
    float sp = LN2 * L;
    float g  = EXP2(nA * L);
    float u  = sp * b2f(bp_c) * b2f(xv_c);
    if (c == 0 && t == 0) u += g * h0[b * Dd + d];
    h = g * h + u;
    p *= g;
    pp[0]    = f2b(h);                       // own addrs: safe in-place
    pp[1024] = f2b(p);
    pp += 2048; px += 1024;
    dt_c = dt_n; bp_c = bp_n; xv_c = xv_n;
  }
  size_t o = ((size_t)b * CCH + c) * Dd + d;
  Pc[o] = p;
  Hl[o] = h;
}

// ---------------------------------------------------------------------------
// S2: sequential carry over 128 chunks; carry-in overwrites Pc.
// 64 blocks x 64 threads; 8-deep register-group prefetch.
// ---------------------------------------------------------------------------
__global__ __launch_bounds__(64) void scan_carry(
    float* __restrict__ Pc, const float* __restrict__ Hl)
{
  const int t = blockIdx.x * 64 + threadIdx.x;   // 0..4095
  const int b = t >> 10;
  const int d = t & 1023;
  const size_t base = (size_t)b * CCH * Dd + d;
  float st = 0.f;
  for (int cg = 0; cg < CCH; cg += 8) {
    float pv[8], hv[8];
#pragma unroll
    for (int j = 0; j < 8; ++j) {
      size_t o = base + (size_t)(cg + j) * Dd;
      pv[j] = Pc[o]; hv[j] = Hl[o];
    }
#pragma unroll
    for (int j = 0; j < 8; ++j) {
      size_t o = base + (size_t)(cg + j) * Dd;
      Pc[o] = st;
      st = pv[j] * st + hv[j];
    }
  }
}

// ---------------------------------------------------------------------------
// S3: chain-free fixup: h(t) = hl(t) + carry * pg(t); h -> gate slot of P.
// ---------------------------------------------------------------------------
__global__ __launch_bounds__(256) void scan_fix(
    short* __restrict__ P, const float* __restrict__ carry)
{
  size_t idx = ((size_t)blockIdx.x * 256 + threadIdx.x) * 4;  // over 16M elems
  const int m  = (int)(idx >> 10);
  const int d0 = (int)(idx & 1023);
  const int b  = m >> 12;
  const int c  = (m & (Sdim - 1)) >> 5;      // s / LCH
  short4v hl4 = *(const short4v*)(P + (size_t)m * 2048 + d0);
  short4v pg4 = *(const short4v*)(P + (size_t)m * 2048 + 1024 + d0);
  floatx4 cv  = *(const floatx4*)(carry + ((size_t)b * CCH + c) * Dd + d0);
  short4v o4;
#pragma unroll
  for (int j = 0; j < 4; j++)
    o4[j] = f2b(b2f(hl4[j]) + cv[j] * b2f(pg4[j]));
  *(short4v*)(P + (size_t)m * 2048 + d0) = o4;
}

// ---------------------------------------------------------------------------
extern "C" void kernel_launch(void* const* d_in, const int* in_sizes, int n_in,
                              void* d_out, int out_size, void* d_ws, size_t ws_size,
                              hipStream_t stream)
{
  const float* x     = (const float*)d_in[0];  // [4,4096,1024] fp32
  const float* h0    = (const float*)d_in[1];  // [4,1024]
  const float* dt_w  = (const float*)d_in[2];  // [1024,1024]
  const float* dt_b  = (const float*)d_in[3];  // [1024]
  const float* A_log = (const float*)d_in[4];  // [1024]
  const float* B_w   = (const float*)d_in[5];  // [1024,1024]
  const float* C_w   = (const float*)d_in[6];  // [1024,1024]
  const float* Dp    = (const float*)d_in[7];  // [1024]
  float* out = (float*)d_out;                  // [4,4096,1024] fp32

  // ws layout (106 MB):
  //   [0,64)    P bf16 [16384][2048]: dt_pre|Bp -> hl|pg -> h|pg
  //   [64,96)   xb bf16 [16384][1024]
  //   [96,102)  wcat bf16 [3072][1024]  (dt_w | B_w | C_w)
  //   [102,104) Pc fp32 [4][128][1024]
  //   [104,106) Hl fp32 [4][128][1024]
  char* ws = (char*)d_ws;
  short* P    = (short*)(ws);
  short* xb   = (short*)(ws + (64ull  << 20));
  short* wcat = (short*)(ws + (96ull  << 20));
  float* Pc   = (float*)(ws + (102ull << 20));
  float* Hl   = (float*)(ws + (104ull << 20));

  // C0: all casts in one launch: (16M + 3M)/8/256 = 9728 blocks
  cast_all<<<9728, 256, 0, stream>>>(x, dt_w, B_w, C_w, xb, wcat);

  // K1: P = x @ [dt_w;B_w]^T  (M=16384, N=2048, K=1024), 256² tiles
  gemm8<short, false><<<dim3(Mdim / 256, 2048 / 256), 512, 0, stream>>>(
      xb, Dd, wcat, Dd, P, 2048, nullptr, nullptr, 0);

  // S1-S3: chunked scan, transcendentals once, fixup chain-free
  scan_local<<<dim3(Bdim * CCH, Dd / 256), 256, 0, stream>>>(
      P, xb, dt_b, A_log, h0, Pc, Hl);
  scan_carry<<<64, 64, 0, stream>>>(Pc, Hl);
  scan_fix<<<(Mdim * Dd / 4) / 256, 256, 0, stream>>>(P, Pc);

  // K6: out = h @ C_w^T + D*x  (h bf16 in P lda=2048; D*x epilogue from xb)
  gemm8<float, true><<<dim3(Mdim / 256, 1024 / 256), 512, 0, stream>>>(
      P, 2048, wcat + 2 * 1024 * 1024, Dd, out, Dd, Dp, xb, Dd);
}

// Round 6
// 293.499 us; speedup vs baseline: 1.0297x; 1.0297x over previous
//
#include <hip/hip_runtime.h>
#include <hip/hip_bf16.h>
#include <stdint.h>
#include <stddef.h>

// SimpleStateSpaceModel: B=4, S=4096, D=1024. FP32 in/out; bf16 MFMA inside.
// Pipeline (106 MB of d_ws):
//   C0 cast_all : x->xb (32MB), {dt_w,B_w,C_w}->wcat (6MB)
//   K1 gemm_k1  : Pdt=x@dt_w^T, Pbp=x@B_w^T   (bf16 out, split arrays)
//   S1 scan_local : g,u from (Pdt,Pbp,xb); in-place -> [hl | pg]
//   S2 scan_carry : sequential combine over 128 chunks
//   S3 scan_fix   : h(t) = hl(t) + carry*pg(t) -> Pdt
//   K6 gemm_k6  : out = h@C_w^T + D*x (xb epilogue), h read from Pdt
// R6: (a) GEMM reverted to R4's 16x16x32 schedule (R5's 32x32 frag needs 32
// rows/column-read over 8 LDS slots -> inherent 4-way bank conflict; 16x16 is
// 2-way=free). (b) P split [16384][2048] -> Pdt+Pbp [16384][1024]: kills all
// 4KB-strided streams (K1 C-write, S1/S3 t-walk, K6 A-staging) -- suspected
// HBM channel aliasing; now every stream is 2KB-strided like proven-fast xb.
// (c) distinct kernel names gemm_k1/gemm_k6 for profiler disambiguation.

#define Bdim 4
#define Sdim 4096
#define Dd   1024
#define Mdim (Bdim * Sdim)      // 16384
#define CCH  128                // scan chunks per sequence
#define LCH  (Sdim / CCH)       // 32 steps per chunk

typedef __attribute__((ext_vector_type(8))) short  short8;
typedef __attribute__((ext_vector_type(4))) short  short4v;
typedef __attribute__((ext_vector_type(4))) float  floatx4;

#if __has_builtin(__builtin_amdgcn_exp2f)
#define EXP2(x) __builtin_amdgcn_exp2f(x)
#else
#define EXP2(x) exp2f(x)
#endif
#if __has_builtin(__builtin_amdgcn_logf)
#define LOG2(x) __builtin_amdgcn_logf(x)
#else
#define LOG2(x) __log2f(x)
#endif
#define LOG2E 1.44269504088896f
#define LN2   0.69314718055995f

__device__ __forceinline__ float b2f(short v) {
  unsigned u = ((unsigned)(unsigned short)v) << 16;
  float f; __builtin_memcpy(&f, &u, 4); return f;
}
// HW RNE bf16 convert
__device__ __forceinline__ short f2b(float f) {
  __hip_bfloat16 h = __float2bfloat16(f);
  short s; __builtin_memcpy(&s, &h, 2); return s;
}

__device__ __forceinline__ short8 ld8f(const float* p) {
  floatx4 lo = *(const floatx4*)p;
  floatx4 hi = *(const floatx4*)(p + 4);
  short8 r;
  r[0] = f2b(lo[0]); r[1] = f2b(lo[1]); r[2] = f2b(lo[2]); r[3] = f2b(lo[3]);
  r[4] = f2b(hi[0]); r[5] = f2b(hi[1]); r[6] = f2b(hi[2]); r[7] = f2b(hi[3]);
  return r;
}

__device__ __forceinline__ void st_out(short* p, float v) { *p = f2b(v); }
__device__ __forceinline__ void st_out(float* p, float v) { *p = v; }

// async 16B global->LDS (DMA). lds dest wave-uniform; lane i -> l + i*16. [m97]
__device__ __forceinline__ void cp16(const void* g, void* l) {
  __builtin_amdgcn_global_load_lds(
      (__attribute__((address_space(1))) void*)g,
      (__attribute__((address_space(3))) void*)l, 16, 0, 0);
}

// ---------------------------------------------------------------------------
// gemm_body: Out[m,n] = sum_k A[m,k]*W[n,k], A/W bf16, K=1024, all row
// strides 1024 (2KB). 256x256 tile, BK=64, 8 waves (2M x 4N), 128x64/wave.
// R4 schedule: per tile 4 phases = C-quadrants (0,0),(0,1),(1,1),(1,0);
// phase = {WBAR(vmcnt4+barrier); ds_read frags; stage next half-tile; MFMA}.
// Steady state 6-8 loads in flight; vmcnt never 0 except epilogue.
// Output: logical col n < NSPLIT -> Out0[n], else Out1[n-NSPLIT].
// ---------------------------------------------------------------------------
#define STGA(bufB, h, kk) do { \
  cp16(Ag + (size_t)((h) * 64) * 1024 + (kk), \
       smc + (bufB) + ((h) * 64 + ldsArow) * 128); \
  cp16(Ag + (size_t)((h) * 64 + 128) * 1024 + (kk), \
       smc + (bufB) + ((h) * 64 + 128 + ldsArow) * 128); \
} while (0)

#define STGB(bufB, h, kk) do { \
  cp16(Bg + (size_t)((h) * 32) * 1024 + (kk), \
       smc + (bufB) + ((h) * 32 + ldsBrow) * 128); \
  cp16(Bg + (size_t)((h) * 32 + 128) * 1024 + (kk), \
       smc + (bufB) + ((h) * 32 + 128 + ldsBrow) * 128); \
} while (0)

#define LDA4(bufB, mh) do { \
  _Pragma("unroll") \
  for (int mf = 0; mf < 4; ++mf) { \
    const char* p_ = smc + (bufB) + (wm + (mh) * 64 + mf * 16 + l16) * 128; \
    a[mf][0] = *(const short8*)(p_ + c0x); \
    a[mf][1] = *(const short8*)(p_ + c1x); \
  } \
} while (0)

#define LDB2(bufB, nh, bb) do { \
  _Pragma("unroll") \
  for (int g = 0; g < 2; ++g) { \
    const char* p_ = smc + (bufB) + (wn + (nh) * 32 + g * 16 + l16) * 128; \
    bb[g][0] = *(const short8*)(p_ + c0x); \
    bb[g][1] = *(const short8*)(p_ + c1x); \
  } \
} while (0)

// 16-MFMA cluster (one C-quadrant over K=64). setprio (T5); trailing
// sched_barrier keeps the cluster ahead of the next raw s_barrier.
#define MM8(mh, nh, bb) do { \
  __builtin_amdgcn_s_setprio(1); \
  _Pragma("unroll") \
  for (int mf = 0; mf < 4; ++mf) { \
    _Pragma("unroll") \
    for (int g = 0; g < 2; ++g) { \
      floatx4 c_ = acc[(mh) * 4 + mf][(nh) * 2 + g]; \
      c_ = __builtin_amdgcn_mfma_f32_16x16x32_bf16(a[mf][0], bb[g][0], c_, 0, 0, 0); \
      c_ = __builtin_amdgcn_mfma_f32_16x16x32_bf16(a[mf][1], bb[g][1], c_, 0, 0, 0); \
      acc[(mh) * 4 + mf][(nh) * 2 + g] = c_; \
    } \
  } \
  __builtin_amdgcn_s_setprio(0); \
  __builtin_amdgcn_sched_barrier(0); \
} while (0)

#define WBAR(n) asm volatile("s_waitcnt vmcnt(" n ")\n\ts_barrier" ::: "memory")
#define BARO()  asm volatile("s_barrier" ::: "memory")

// one full K-tile, all staging unconditional (hot loop only).
#define KSTEP(AB, BBUF, AN, BN, kk) do { \
  WBAR("4"); \
  LDA4(AB, 0); \
  LDB2(BBUF, 0, b0); \
  STGA(AN, 0, kk); \
  MM8(0, 0, b0); \
  WBAR("4"); \
  LDB2(BBUF, 1, b1); \
  STGB(BN, 0, kk); \
  MM8(0, 1, b1); \
  WBAR("4"); \
  LDA4(AB, 1); \
  STGB(BN, 1, kk); \
  MM8(1, 1, b1); \
  BARO(); \
  STGA(AN, 1, kk); \
  MM8(1, 0, b0); \
} while (0)

template <typename OT, bool FUSE, int NSPLIT>
__device__ __forceinline__ void gemm_body(
    const short* __restrict__ A,          // [M][1024] bf16
    const short* __restrict__ W,          // [N][1024] bf16 row-major
    OT* __restrict__ Out0, OT* __restrict__ Out1,   // [M][1024] each
    const float* __restrict__ Dp, const short* __restrict__ Xr)
{
  __shared__ short smem[65536];   // 128 KiB: Abuf0|Abuf1|Bbuf0|Bbuf1, 32K each
  char* smc = (char*)smem;

  const int tid  = threadIdx.x;
  const int lane = tid & 63, wv = tid >> 6;
  const int quad = lane >> 4, l16 = lane & 15;
  const int wm = (wv & 1) << 7;           // 0 / 128
  const int wn = (wv >> 1) << 6;          // 0,64,128,192
  const int m0 = blockIdx.x << 8;
  const int n0 = blockIdx.y << 8;

  // output base for this block's 256-col strip (strip never straddles NSPLIT)
  OT* Ob = (n0 < NSPLIT) ? Out0 : Out1;
  const int nb0 = (n0 < NSPLIT) ? n0 : n0 - NSPLIT;

  // read-side swizzle: phys col-byte = logical ^ ((row&7)<<4); row&7 == l16&7
  const int sx  = (l16 & 7) << 4;
  const int c0x = (quad << 4) ^ sx;            // ks=0 fragment column
  const int c1x = (64 + (quad << 4)) ^ sx;     // ks=1 fragment column

  // per-thread staging source bases (pre-swizzled global column)
  const int r0 = tid >> 3;                                  // 0..63
  const int sk = (((tid & 7) ^ (r0 & 7)) << 3);             // elems, <64
  const short* Ag = A + (size_t)(m0 + r0) * 1024 + sk;
  const short* Bg = W + (size_t)(n0 + ((r0 >> 5) << 6) + (r0 & 31)) * 1024 + sk;
  const int ldsArow = wv << 3;                              // wave-uniform
  const int ldsBrow = ((wv >> 2) << 6) + ((wv << 3) & 31);  // wave-uniform

  short8 a[4][2], b0[2][2], b1[2][2];
  floatx4 acc[8][4] = {};

  // prologue: stage tile 0 into buf0, consumption order A0, B0, B1, A1
  STGA(0, 0, 0);
  STGB(65536, 0, 0);
  STGB(65536, 1, 0);
  STGA(0, 1, 0);

  // hot loop: tiles 0..13, 2 per iteration, literal buffer bases.
  for (int t = 0; t < 14; t += 2) {
    KSTEP(0,     65536, 32768, 98304, (t + 1) << 6);
    KSTEP(32768, 98304, 0,     65536, (t + 2) << 6);
  }
  // tile 14 (even, still stages tile 15)
  KSTEP(0, 65536, 32768, 98304, 15 << 6);

  // tile 15 epilogue (cb=1, no staging; drain 4 -> 2 -> 0)
  WBAR("4");
  LDA4(32768, 0);
  LDB2(98304, 0, b0);
  MM8(0, 0, b0);
  WBAR("2");
  LDB2(98304, 1, b1);
  MM8(0, 1, b1);
  WBAR("0");
  LDA4(32768, 1);
  MM8(1, 1, b1);
  BARO();
  MM8(1, 0, b0);

  // C/D layout: row = quad*4 + r, col = l16  [verified m89/m91]
#pragma unroll
  for (int i = 0; i < 8; ++i) {
#pragma unroll
    for (int j = 0; j < 4; ++j) {
#pragma unroll
      for (int r = 0; r < 4; ++r) {
        int m  = m0 + wm + i * 16 + quad * 4 + r;
        int nc = wn + j * 16 + l16;            // col within strip
        float v = acc[i][j][r];
        if (FUSE) {
          int n = n0 + nc;
          v += Dp[n] * b2f(Xr[(size_t)m * 1024 + n]);
        }
        st_out(Ob + (size_t)m * 1024 + (nb0 + nc), v);
      }
    }
  }
}

__global__ __launch_bounds__(512, 2) void gemm_k1(
    const short* __restrict__ A, const short* __restrict__ W,
    short* __restrict__ O0, short* __restrict__ O1)
{
  gemm_body<short, false, 1024>(A, W, O0, O1, nullptr, nullptr);
}

__global__ __launch_bounds__(512, 2) void gemm_k6(
    const short* __restrict__ A, const short* __restrict__ W,
    float* __restrict__ O,
    const float* __restrict__ Dp, const short* __restrict__ Xr)
{
  gemm_body<float, true, (1 << 30)>(A, W, O, nullptr, Dp, Xr);
}

// ---------------------------------------------------------------------------
// C0: fused cast fp32->bf16 for x (16M elems) and the 3 weights (1M each).
// ---------------------------------------------------------------------------
__global__ __launch_bounds__(256) void cast_all(
    const float* __restrict__ x, const float* __restrict__ dt_w,
    const float* __restrict__ B_w, const float* __restrict__ C_w,
    short* __restrict__ xb, short* __restrict__ wcat)
{
  size_t i = ((size_t)blockIdx.x * 256 + threadIdx.x) * 8;
  const size_t NX = (size_t)Mdim * Dd;           // 16,777,216
  const size_t NW = (size_t)Dd * Dd;             // 1,048,576
  if (i < NX) {
    *(short8*)(xb + i) = ld8f(x + i);
  } else {
    size_t j = i - NX;
    const float* src = (j < NW) ? (dt_w + j)
                     : (j < 2 * NW) ? (B_w + (j - NW))
                                    : (C_w + (j - 2 * NW));
    *(short8*)(wcat + j) = ld8f(src);
  }
}

// ---------------------------------------------------------------------------
// S1: single transcendental pass, 1 d per thread (8192 waves).
// Gate math: z = dt_pre + dt_b; e = 2^(z*log2e); L = log2(1+e);
//   sp = ln2*L (softplus); g = 2^(nA*L)  [= exp(sp*nA)]; u = sp*Bp*x.
// All streams 2KB-strided (split P arrays).
// ---------------------------------------------------------------------------
__global__ __launch_bounds__(256) void scan_local(
    short* __restrict__ Pdt, short* __restrict__ Pbp,
    const short* __restrict__ xb,
    const float* __restrict__ dt_b, const float* __restrict__ A_log,
    const float* __restrict__ h0,
    float* __restrict__ Pc, float* __restrict__ Hl)
{
  const int b = blockIdx.x >> 7;
  const int c = blockIdx.x & 127;
  const int d = blockIdx.y * 256 + threadIdx.x;

  const float db = dt_b[d];
  const float nA = -EXP2(A_log[d] * LOG2E);

  const size_t mrow = (size_t)b * Sdim + (size_t)c * LCH;
  short* pd = Pdt + mrow * 1024 + d;
  short* pb = Pbp + mrow * 1024 + d;
  const short* px = xb + mrow * 1024 + d;

  float p = 1.f, h = 0.f;
  short dt_c = pd[0], bp_c = pb[0], xv_c = px[0];
  for (int t = 0; t < LCH; ++t) {
    short dt_n = 0, bp_n = 0, xv_n = 0;
    if (t + 1 < LCH) {                       // prefetch above the serial chain
      dt_n = pd[1024]; bp_n = pb[1024]; xv_n = px[1024];
    }
    float z  = b2f(dt_c) + db;
    float e  = EXP2(z * LOG2E);
    float L  = LOG2(1.f + e);
    float sp = LN2 * L;
    float g  = EXP2(nA * L);
    float u  = sp * b2f(bp_c) * b2f(xv_c);
    if (c == 0 && t == 0) u += g * h0[b * Dd + d];
    h = g * h + u;
    p *= g;
    pd[0] = f2b(h);                          // own addrs: safe in-place
    pb[0] = f2b(p);
    pd += 1024; pb += 1024; px += 1024;
    dt_c = dt_n; bp_c = bp_n; xv_c = xv_n;
  }
  size_t o = ((size_t)b * CCH + c) * Dd + d;
  Pc[o] = p;
  Hl[o] = h;
}

// ---------------------------------------------------------------------------
// S2: sequential carry over 128 chunks; carry-in overwrites Pc.
// 64 blocks x 64 threads; 8-deep register-group prefetch.
// ---------------------------------------------------------------------------
__global__ __launch_bounds__(64) void scan_carry(
    float* __restrict__ Pc, const float* __restrict__ Hl)
{
  const int t = blockIdx.x * 64 + threadIdx.x;   // 0..4095
  const int b = t >> 10;
  const int d = t & 1023;
  const size_t base = (size_t)b * CCH * Dd + d;
  float st = 0.f;
  for (int cg = 0; cg < CCH; cg += 8) {
    float pv[8], hv[8];
#pragma unroll
    for (int j = 0; j < 8; ++j) {
      size_t o = base + (size_t)(cg + j) * Dd;
      pv[j] = Pc[o]; hv[j] = Hl[o];
    }
#pragma unroll
    for (int j = 0; j < 8; ++j) {
      size_t o = base + (size_t)(cg + j) * Dd;
      Pc[o] = st;
      st = pv[j] * st + hv[j];
    }
  }
}

// ---------------------------------------------------------------------------
// S3: chain-free fixup: h(t) = hl(t) + carry * pg(t); h -> Pdt.
// ---------------------------------------------------------------------------
__global__ __launch_bounds__(256) void scan_fix(
    short* __restrict__ Pdt, const short* __restrict__ Pbp,
    const float* __restrict__ carry)
{
  size_t idx = ((size_t)blockIdx.x * 256 + threadIdx.x) * 4;  // over 16M elems
  const int m  = (int)(idx >> 10);
  const int d0 = (int)(idx & 1023);
  const int b  = m >> 12;
  const int c  = (m & (Sdim - 1)) >> 5;      // s / LCH
  short4v hl4 = *(const short4v*)(Pdt + (size_t)m * 1024 + d0);
  short4v pg4 = *(const short4v*)(Pbp + (size_t)m * 1024 + d0);
  floatx4 cv  = *(const floatx4*)(carry + ((size_t)b * CCH + c) * Dd + d0);
  short4v o4;
#pragma unroll
  for (int j = 0; j < 4; j++)
    o4[j] = f2b(b2f(hl4[j]) + cv[j] * b2f(pg4[j]));
  *(short4v*)(Pdt + (size_t)m * 1024 + d0) = o4;
}

// ---------------------------------------------------------------------------
extern "C" void kernel_launch(void* const* d_in, const int* in_sizes, int n_in,
                              void* d_out, int out_size, void* d_ws, size_t ws_size,
                              hipStream_t stream)
{
  const float* x     = (const float*)d_in[0];  // [4,4096,1024] fp32
  const float* h0    = (const float*)d_in[1];  // [4,1024]
  const float* dt_w  = (const float*)d_in[2];  // [1024,1024]
  const float* dt_b  = (const float*)d_in[3];  // [1024]
  const float* A_log = (const float*)d_in[4];  // [1024]
  const float* B_w   = (const float*)d_in[5];  // [1024,1024]
  const float* C_w   = (const float*)d_in[6];  // [1024,1024]
  const float* Dp    = (const float*)d_in[7];  // [1024]
  float* out = (float*)d_out;                  // [4,4096,1024] fp32

  // ws layout (106 MB):
  //   [0,32)    Pdt bf16 [16384][1024]: dt_pre -> hl -> h
  //   [32,64)   Pbp bf16 [16384][1024]: Bp -> pg
  //   [64,96)   xb bf16 [16384][1024]
  //   [96,102)  wcat bf16 [3072][1024]  (dt_w | B_w | C_w)
  //   [102,104) Pc fp32 [4][128][1024]
  //   [104,106) Hl fp32 [4][128][1024]
  char* ws = (char*)d_ws;
  short* Pdt  = (short*)(ws);
  short* Pbp  = (short*)(ws + (32ull  << 20));
  short* xb   = (short*)(ws + (64ull  << 20));
  short* wcat = (short*)(ws + (96ull  << 20));
  float* Pc   = (float*)(ws + (102ull << 20));
  float* Hl   = (float*)(ws + (104ull << 20));

  // C0: all casts in one launch: (16M + 3M)/8/256 = 9728 blocks
  cast_all<<<9728, 256, 0, stream>>>(x, dt_w, B_w, C_w, xb, wcat);

  // K1: Pdt|Pbp = x @ [dt_w;B_w]^T  (M=16384, N=2048, K=1024), 256² tiles
  gemm_k1<<<dim3(Mdim / 256, 2048 / 256), 512, 0, stream>>>(
      xb, wcat, Pdt, Pbp);

  // S1-S3: chunked scan, transcendentals once, fixup chain-free
  scan_local<<<dim3(Bdim * CCH, Dd / 256), 256, 0, stream>>>(
      Pdt, Pbp, xb, dt_b, A_log, h0, Pc, Hl);
  scan_carry<<<64, 64, 0, stream>>>(Pc, Hl);
  scan_fix<<<(Mdim * Dd / 4) / 256, 256, 0, stream>>>(Pdt, Pbp, Pc);

  // K6: out = h @ C_w^T + D*x  (h bf16 in Pdt; D*x epilogue from xb)
  gemm_k6<<<dim3(Mdim / 256, 1024 / 256), 512, 0, stream>>>(
      Pdt, wcat + 2 * 1024 * 1024, out, Dp, xb);
}

// Round 7
// 285.282 us; speedup vs baseline: 1.0594x; 1.0288x over previous
//
#include <hip/hip_runtime.h>
#include <hip/hip_bf16.h>
#include <stdint.h>
#include <stddef.h>

// SimpleStateSpaceModel: B=4, S=4096, D=1024. FP32 in/out; bf16 MFMA inside.
// Pipeline (106 MB of d_ws):
//   C0 cast_all : x->xb (32MB), {dt_w,B_w,C_w}->wcat (6MB)
//   K1 gemm_k1  : Pdt=x@dt_w^T, Pbp=x@B_w^T   (bf16 out, split arrays)
//   S1 scan_local : g,u from (Pdt,Pbp,xb); in-place -> [hl | pg]
//   S2 scan_carry : sequential combine over 128 chunks
//   S3 scan_fix   : h(t) = hl(t) + carry*pg(t) -> Pdt
//   K6 gemm_k6  : out = h@C_w^T + D*x (xb epilogue), h read from Pdt
// R7: S1 re-vectorized to 4 d/thread short4v (8B/lane; was 2B/lane scalar --
// G13: scalar bf16 ~2-2.5x slower) with a depth-2 register ring so the serial
// h-chain never waits on memory (ILP replaces the lost TLP; 2048 waves).
// h0-fold moved to h-init (algebraically identical). S3 widened to short8
// (16B/lane). GEMMs byte-identical to R6 (control).

#define Bdim 4
#define Sdim 4096
#define Dd   1024
#define Mdim (Bdim * Sdim)      // 16384
#define CCH  128                // scan chunks per sequence
#define LCH  (Sdim / CCH)       // 32 steps per chunk

typedef __attribute__((ext_vector_type(8))) short  short8;
typedef __attribute__((ext_vector_type(4))) short  short4v;
typedef __attribute__((ext_vector_type(4))) float  floatx4;

#if __has_builtin(__builtin_amdgcn_exp2f)
#define EXP2(x) __builtin_amdgcn_exp2f(x)
#else
#define EXP2(x) exp2f(x)
#endif
#if __has_builtin(__builtin_amdgcn_logf)
#define LOG2(x) __builtin_amdgcn_logf(x)
#else
#define LOG2(x) __log2f(x)
#endif
#define LOG2E 1.44269504088896f
#define LN2   0.69314718055995f

__device__ __forceinline__ float b2f(short v) {
  unsigned u = ((unsigned)(unsigned short)v) << 16;
  float f; __builtin_memcpy(&f, &u, 4); return f;
}
// HW RNE bf16 convert
__device__ __forceinline__ short f2b(float f) {
  __hip_bfloat16 h = __float2bfloat16(f);
  short s; __builtin_memcpy(&s, &h, 2); return s;
}

__device__ __forceinline__ short8 ld8f(const float* p) {
  floatx4 lo = *(const floatx4*)p;
  floatx4 hi = *(const floatx4*)(p + 4);
  short8 r;
  r[0] = f2b(lo[0]); r[1] = f2b(lo[1]); r[2] = f2b(lo[2]); r[3] = f2b(lo[3]);
  r[4] = f2b(hi[0]); r[5] = f2b(hi[1]); r[6] = f2b(hi[2]); r[7] = f2b(hi[3]);
  return r;
}

__device__ __forceinline__ void st_out(short* p, float v) { *p = f2b(v); }
__device__ __forceinline__ void st_out(float* p, float v) { *p = v; }

// async 16B global->LDS (DMA). lds dest wave-uniform; lane i -> l + i*16. [m97]
__device__ __forceinline__ void cp16(const void* g, void* l) {
  __builtin_amdgcn_global_load_lds(
      (__attribute__((address_space(1))) void*)g,
      (__attribute__((address_space(3))) void*)l, 16, 0, 0);
}

// ---------------------------------------------------------------------------
// gemm_body: Out[m,n] = sum_k A[m,k]*W[n,k], A/W bf16, K=1024, all row
// strides 1024 (2KB). 256x256 tile, BK=64, 8 waves (2M x 4N), 128x64/wave.
// R4 schedule: per tile 4 phases = C-quadrants (0,0),(0,1),(1,1),(1,0);
// phase = {WBAR(vmcnt4+barrier); ds_read frags; stage next half-tile; MFMA}.
// Steady state 6-8 loads in flight; vmcnt never 0 except epilogue.
// Output: logical col n < NSPLIT -> Out0[n], else Out1[n-NSPLIT].
// ---------------------------------------------------------------------------
#define STGA(bufB, h, kk) do { \
  cp16(Ag + (size_t)((h) * 64) * 1024 + (kk), \
       smc + (bufB) + ((h) * 64 + ldsArow) * 128); \
  cp16(Ag + (size_t)((h) * 64 + 128) * 1024 + (kk), \
       smc + (bufB) + ((h) * 64 + 128 + ldsArow) * 128); \
} while (0)

#define STGB(bufB, h, kk) do { \
  cp16(Bg + (size_t)((h) * 32) * 1024 + (kk), \
       smc + (bufB) + ((h) * 32 + ldsBrow) * 128); \
  cp16(Bg + (size_t)((h) * 32 + 128) * 1024 + (kk), \
       smc + (bufB) + ((h) * 32 + 128 + ldsBrow) * 128); \
} while (0)

#define LDA4(bufB, mh) do { \
  _Pragma("unroll") \
  for (int mf = 0; mf < 4; ++mf) { \
    const char* p_ = smc + (bufB) + (wm + (mh) * 64 + mf * 16 + l16) * 128; \
    a[mf][0] = *(const short8*)(p_ + c0x); \
    a[mf][1] = *(const short8*)(p_ + c1x); \
  } \
} while (0)

#define LDB2(bufB, nh, bb) do { \
  _Pragma("unroll") \
  for (int g = 0; g < 2; ++g) { \
    const char* p_ = smc + (bufB) + (wn + (nh) * 32 + g * 16 + l16) * 128; \
    bb[g][0] = *(const short8*)(p_ + c0x); \
    bb[g][1] = *(const short8*)(p_ + c1x); \
  } \
} while (0)

// 16-MFMA cluster (one C-quadrant over K=64). setprio (T5); trailing
// sched_barrier keeps the cluster ahead of the next raw s_barrier.
#define MM8(mh, nh, bb) do { \
  __builtin_amdgcn_s_setprio(1); \
  _Pragma("unroll") \
  for (int mf = 0; mf < 4; ++mf) { \
    _Pragma("unroll") \
    for (int g = 0; g < 2; ++g) { \
      floatx4 c_ = acc[(mh) * 4 + mf][(nh) * 2 + g]; \
      c_ = __builtin_amdgcn_mfma_f32_16x16x32_bf16(a[mf][0], bb[g][0], c_, 0, 0, 0); \
      c_ = __builtin_amdgcn_mfma_f32_16x16x32_bf16(a[mf][1], bb[g][1], c_, 0, 0, 0); \
      acc[(mh) * 4 + mf][(nh) * 2 + g] = c_; \
    } \
  } \
  __builtin_amdgcn_s_setprio(0); \
  __builtin_amdgcn_sched_barrier(0); \
} while (0)

#define WBAR(n) asm volatile("s_waitcnt vmcnt(" n ")\n\ts_barrier" ::: "memory")
#define BARO()  asm volatile("s_barrier" ::: "memory")

// one full K-tile, all staging unconditional (hot loop only).
#define KSTEP(AB, BBUF, AN, BN, kk) do { \
  WBAR("4"); \
  LDA4(AB, 0); \
  LDB2(BBUF, 0, b0); \
  STGA(AN, 0, kk); \
  MM8(0, 0, b0); \
  WBAR("4"); \
  LDB2(BBUF, 1, b1); \
  STGB(BN, 0, kk); \
  MM8(0, 1, b1); \
  WBAR("4"); \
  LDA4(AB, 1); \
  STGB(BN, 1, kk); \
  MM8(1, 1, b1); \
  BARO(); \
  STGA(AN, 1, kk); \
  MM8(1, 0, b0); \
} while (0)

template <typename OT, bool FUSE, int NSPLIT>
__device__ __forceinline__ void gemm_body(
    const short* __restrict__ A,          // [M][1024] bf16
    const short* __restrict__ W,          // [N][1024] bf16 row-major
    OT* __restrict__ Out0, OT* __restrict__ Out1,   // [M][1024] each
    const float* __restrict__ Dp, const short* __restrict__ Xr)
{
  __shared__ short smem[65536];   // 128 KiB: Abuf0|Abuf1|Bbuf0|Bbuf1, 32K each
  char* smc = (char*)smem;

  const int tid  = threadIdx.x;
  const int lane = tid & 63, wv = tid >> 6;
  const int quad = lane >> 4, l16 = lane & 15;
  const int wm = (wv & 1) << 7;           // 0 / 128
  const int wn = (wv >> 1) << 6;          // 0,64,128,192
  const int m0 = blockIdx.x << 8;
  const int n0 = blockIdx.y << 8;

  // output base for this block's 256-col strip (strip never straddles NSPLIT)
  OT* Ob = (n0 < NSPLIT) ? Out0 : Out1;
  const int nb0 = (n0 < NSPLIT) ? n0 : n0 - NSPLIT;

  // read-side swizzle: phys col-byte = logical ^ ((row&7)<<4); row&7 == l16&7
  const int sx  = (l16 & 7) << 4;
  const int c0x = (quad << 4) ^ sx;            // ks=0 fragment column
  const int c1x = (64 + (quad << 4)) ^ sx;     // ks=1 fragment column

  // per-thread staging source bases (pre-swizzled global column)
  const int r0 = tid >> 3;                                  // 0..63
  const int sk = (((tid & 7) ^ (r0 & 7)) << 3);             // elems, <64
  const short* Ag = A + (size_t)(m0 + r0) * 1024 + sk;
  const short* Bg = W + (size_t)(n0 + ((r0 >> 5) << 6) + (r0 & 31)) * 1024 + sk;
  const int ldsArow = wv << 3;                              // wave-uniform
  const int ldsBrow = ((wv >> 2) << 6) + ((wv << 3) & 31);  // wave-uniform

  short8 a[4][2], b0[2][2], b1[2][2];
  floatx4 acc[8][4] = {};

  // prologue: stage tile 0 into buf0, consumption order A0, B0, B1, A1
  STGA(0, 0, 0);
  STGB(65536, 0, 0);
  STGB(65536, 1, 0);
  STGA(0, 1, 0);

  // hot loop: tiles 0..13, 2 per iteration, literal buffer bases.
  for (int t = 0; t < 14; t += 2) {
    KSTEP(0,     65536, 32768, 98304, (t + 1) << 6);
    KSTEP(32768, 98304, 0,     65536, (t + 2) << 6);
  }
  // tile 14 (even, still stages tile 15)
  KSTEP(0, 65536, 32768, 98304, 15 << 6);

  // tile 15 epilogue (cb=1, no staging; drain 4 -> 2 -> 0)
  WBAR("4");
  LDA4(32768, 0);
  LDB2(98304, 0, b0);
  MM8(0, 0, b0);
  WBAR("2");
  LDB2(98304, 1, b1);
  MM8(0, 1, b1);
  WBAR("0");
  LDA4(32768, 1);
  MM8(1, 1, b1);
  BARO();
  MM8(1, 0, b0);

  // C/D layout: row = quad*4 + r, col = l16  [verified m89/m91]
#pragma unroll
  for (int i = 0; i < 8; ++i) {
#pragma unroll
    for (int j = 0; j < 4; ++j) {
#pragma unroll
      for (int r = 0; r < 4; ++r) {
        int m  = m0 + wm + i * 16 + quad * 4 + r;
        int nc = wn + j * 16 + l16;            // col within strip
        float v = acc[i][j][r];
        if (FUSE) {
          int n = n0 + nc;
          v += Dp[n] * b2f(Xr[(size_t)m * 1024 + n]);
        }
        st_out(Ob + (size_t)m * 1024 + (nb0 + nc), v);
      }
    }
  }
}

__global__ __launch_bounds__(512, 2) void gemm_k1(
    const short* __restrict__ A, const short* __restrict__ W,
    short* __restrict__ O0, short* __restrict__ O1)
{
  gemm_body<short, false, 1024>(A, W, O0, O1, nullptr, nullptr);
}

__global__ __launch_bounds__(512, 2) void gemm_k6(
    const short* __restrict__ A, const short* __restrict__ W,
    float* __restrict__ O,
    const float* __restrict__ Dp, const short* __restrict__ Xr)
{
  gemm_body<float, true, (1 << 30)>(A, W, O, nullptr, Dp, Xr);
}

// ---------------------------------------------------------------------------
// C0: fused cast fp32->bf16 for x (16M elems) and the 3 weights (1M each).
// ---------------------------------------------------------------------------
__global__ __launch_bounds__(256) void cast_all(
    const float* __restrict__ x, const float* __restrict__ dt_w,
    const float* __restrict__ B_w, const float* __restrict__ C_w,
    short* __restrict__ xb, short* __restrict__ wcat)
{
  size_t i = ((size_t)blockIdx.x * 256 + threadIdx.x) * 8;
  const size_t NX = (size_t)Mdim * Dd;           // 16,777,216
  const size_t NW = (size_t)Dd * Dd;             // 1,048,576
  if (i < NX) {
    *(short8*)(xb + i) = ld8f(x + i);
  } else {
    size_t j = i - NX;
    const float* src = (j < NW) ? (dt_w + j)
                     : (j < 2 * NW) ? (B_w + (j - NW))
                                    : (C_w + (j - 2 * NW));
    *(short8*)(wcat + j) = ld8f(src);
  }
}

// ---------------------------------------------------------------------------
// S1: single transcendental pass, 4 d/thread short4v (8B/lane), depth-2
// register ring: steps t,t+1 resident; t+2,t+3 issued before the serial
// chain so loads never gate it. Ring over-reads <=2 rows past the chunk --
// lands in the next ws array (Pdt->Pbp->xb->wcat), values unused: safe.
// Gate math: z = dt_pre + dt_b; e = 2^(z*log2e); L = log2(1+e);
//   sp = ln2*L (softplus); g = 2^(nA*L); u = sp*Bp*x.
// h0 fold as init: h(c==0) = h0 (identical algebra to u += g*h0 at t=0).
// ---------------------------------------------------------------------------
#define S1STEP(DT, BP, XV, OFF) do { \
  short4v o_h, o_p; \
  _Pragma("unroll") \
  for (int j = 0; j < 4; ++j) { \
    float z = b2f(DT[j]) + db4[j]; \
    float e = EXP2(z * LOG2E); \
    float L = LOG2(1.f + e); \
    float g = EXP2(nA[j] * L); \
    float u = (LN2 * L) * b2f(BP[j]) * b2f(XV[j]); \
    h[j] = g * h[j] + u; \
    p[j] *= g; \
    o_h[j] = f2b(h[j]); \
    o_p[j] = f2b(p[j]); \
  } \
  *(short4v*)(pd + (OFF)) = o_h; \
  *(short4v*)(pb + (OFF)) = o_p; \
} while (0)

__global__ __launch_bounds__(256) void scan_local(
    short* __restrict__ Pdt, short* __restrict__ Pbp,
    const short* __restrict__ xb,
    const float* __restrict__ dt_b, const float* __restrict__ A_log,
    const float* __restrict__ h0,
    float* __restrict__ Pc, float* __restrict__ Hl)
{
  const int b  = blockIdx.x >> 7;
  const int c  = blockIdx.x & 127;
  const int d0 = threadIdx.x * 4;

  floatx4 db4 = *(const floatx4*)(dt_b + d0);
  floatx4 al4 = *(const floatx4*)(A_log + d0);
  float nA[4];
#pragma unroll
  for (int j = 0; j < 4; ++j) nA[j] = -EXP2(al4[j] * LOG2E);

  const size_t base = ((size_t)b * Sdim + (size_t)c * LCH) * 1024 + d0;
  short* pd = Pdt + base;
  short* pb = Pbp + base;
  const short* px = xb + base;

  float p[4] = {1.f, 1.f, 1.f, 1.f}, h[4] = {};
  if (c == 0) {
    floatx4 h04 = *(const floatx4*)(h0 + b * Dd + d0);
#pragma unroll
    for (int j = 0; j < 4; ++j) h[j] = h04[j];
  }

  // prime ring: steps 0,1 resident
  short4v dtA = *(const short4v*)(pd);
  short4v bpA = *(const short4v*)(pb);
  short4v xvA = *(const short4v*)(px);
  short4v dtB = *(const short4v*)(pd + 1024);
  short4v bpB = *(const short4v*)(pb + 1024);
  short4v xvB = *(const short4v*)(px + 1024);

  for (int t = 0; t < LCH; t += 2) {
    // issue t+2 loads above the serial chain
    short4v dtN0 = *(const short4v*)(pd + 2048);
    short4v bpN0 = *(const short4v*)(pb + 2048);
    short4v xvN0 = *(const short4v*)(px + 2048);
    S1STEP(dtA, bpA, xvA, 0);
    // issue t+3 loads
    short4v dtN1 = *(const short4v*)(pd + 3072);
    short4v bpN1 = *(const short4v*)(pb + 3072);
    short4v xvN1 = *(const short4v*)(px + 3072);
    S1STEP(dtB, bpB, xvB, 1024);
    pd += 2048; pb += 2048; px += 2048;
    dtA = dtN0; bpA = bpN0; xvA = xvN0;
    dtB = dtN1; bpB = bpN1; xvB = xvN1;
  }

  size_t o = ((size_t)b * CCH + c) * Dd + d0;
  *(floatx4*)(Pc + o) = floatx4{p[0], p[1], p[2], p[3]};
  *(floatx4*)(Hl + o) = floatx4{h[0], h[1], h[2], h[3]};
}

// ---------------------------------------------------------------------------
// S2: sequential carry over 128 chunks; carry-in overwrites Pc.
// 64 blocks x 64 threads; 8-deep register-group prefetch.
// ---------------------------------------------------------------------------
__global__ __launch_bounds__(64) void scan_carry(
    float* __restrict__ Pc, const float* __restrict__ Hl)
{
  const int t = blockIdx.x * 64 + threadIdx.x;   // 0..4095
  const int b = t >> 10;
  const int d = t & 1023;
  const size_t base = (size_t)b * CCH * Dd + d;
  float st = 0.f;
  for (int cg = 0; cg < CCH; cg += 8) {
    float pv[8], hv[8];
#pragma unroll
    for (int j = 0; j < 8; ++j) {
      size_t o = base + (size_t)(cg + j) * Dd;
      pv[j] = Pc[o]; hv[j] = Hl[o];
    }
#pragma unroll
    for (int j = 0; j < 8; ++j) {
      size_t o = base + (size_t)(cg + j) * Dd;
      Pc[o] = st;
      st = pv[j] * st + hv[j];
    }
  }
}

// ---------------------------------------------------------------------------
// S3: chain-free fixup: h(t) = hl(t) + carry * pg(t); h -> Pdt.
// 8 elems/thread short8 (16B/lane).
// ---------------------------------------------------------------------------
__global__ __launch_bounds__(256) void scan_fix(
    short* __restrict__ Pdt, const short* __restrict__ Pbp,
    const float* __restrict__ carry)
{
  size_t idx = ((size_t)blockIdx.x * 256 + threadIdx.x) * 8;  // over 16M elems
  const int m  = (int)(idx >> 10);
  const int d0 = (int)(idx & 1023);
  const int b  = m >> 12;
  const int c  = (m & (Sdim - 1)) >> 5;      // s / LCH
  short8 hl8 = *(const short8*)(Pdt + (size_t)m * 1024 + d0);
  short8 pg8 = *(const short8*)(Pbp + (size_t)m * 1024 + d0);
  const float* cp = carry + ((size_t)b * CCH + c) * Dd + d0;
  floatx4 cv0 = *(const floatx4*)(cp);
  floatx4 cv1 = *(const floatx4*)(cp + 4);
  short8 o8;
#pragma unroll
  for (int j = 0; j < 4; j++)
    o8[j] = f2b(b2f(hl8[j]) + cv0[j] * b2f(pg8[j]));
#pragma unroll
  for (int j = 0; j < 4; j++)
    o8[4 + j] = f2b(b2f(hl8[4 + j]) + cv1[j] * b2f(pg8[4 + j]));
  *(short8*)(Pdt + (size_t)m * 1024 + d0) = o8;
}

// ---------------------------------------------------------------------------
extern "C" void kernel_launch(void* const* d_in, const int* in_sizes, int n_in,
                              void* d_out, int out_size, void* d_ws, size_t ws_size,
                              hipStream_t stream)
{
  const float* x     = (const float*)d_in[0];  // [4,4096,1024] fp32
  const float* h0    = (const float*)d_in[1];  // [4,1024]
  const float* dt_w  = (const float*)d_in[2];  // [1024,1024]
  const float* dt_b  = (const float*)d_in[3];  // [1024]
  const float* A_log = (const float*)d_in[4];  // [1024]
  const float* B_w   = (const float*)d_in[5];  // [1024,1024]
  const float* C_w   = (const float*)d_in[6];  // [1024,1024]
  const float* Dp    = (const float*)d_in[7];  // [1024]
  float* out = (float*)d_out;                  // [4,4096,1024] fp32

  // ws layout (106 MB):
  //   [0,32)    Pdt bf16 [16384][1024]: dt_pre -> hl -> h
  //   [32,64)   Pbp bf16 [16384][1024]: Bp -> pg
  //   [64,96)   xb bf16 [16384][1024]
  //   [96,102)  wcat bf16 [3072][1024]  (dt_w | B_w | C_w)
  //   [102,104) Pc fp32 [4][128][1024]
  //   [104,106) Hl fp32 [4][128][1024]
  char* ws = (char*)d_ws;
  short* Pdt  = (short*)(ws);
  short* Pbp  = (short*)(ws + (32ull  << 20));
  short* xb   = (short*)(ws + (64ull  << 20));
  short* wcat = (short*)(ws + (96ull  << 20));
  float* Pc   = (float*)(ws + (102ull << 20));
  float* Hl   = (float*)(ws + (104ull << 20));

  // C0: all casts in one launch: (16M + 3M)/8/256 = 9728 blocks
  cast_all<<<9728, 256, 0, stream>>>(x, dt_w, B_w, C_w, xb, wcat);

  // K1: Pdt|Pbp = x @ [dt_w;B_w]^T  (M=16384, N=2048, K=1024), 256² tiles
  gemm_k1<<<dim3(Mdim / 256, 2048 / 256), 512, 0, stream>>>(
      xb, wcat, Pdt, Pbp);

  // S1-S3: chunked scan, transcendentals once, fixup chain-free
  scan_local<<<Bdim * CCH, 256, 0, stream>>>(
      Pdt, Pbp, xb, dt_b, A_log, h0, Pc, Hl);
  scan_carry<<<64, 64, 0, stream>>>(Pc, Hl);
  scan_fix<<<(Mdim * Dd / 8) / 256, 256, 0, stream>>>(Pdt, Pbp, Pc);

  // K6: out = h @ C_w^T + D*x  (h bf16 in Pdt; D*x epilogue from xb)
  gemm_k6<<<dim3(Mdim / 256, 1024 / 256), 512, 0, stream>>>(
      Pdt, wcat + 2 * 1024 * 1024, out, Dp, xb);
}